// Round 1
// baseline (120.908 us; speedup 1.0000x reference)
//
#include <hip/hip_runtime.h>

// Problem constants (fixed by setup_inputs): B=4, N=4096, K=512.
#define BB 4
#define NN 4096
#define KK 512
#define BLOCK 256
#define ROWS 16            // rows of N per block -> (BB*NN)/ROWS = 1024 blocks

static constexpr float W_P  = 1.0f;
static constexpr float W_C  = 1.0f;
static constexpr float EPSV = 1e-6f;

// Symmetric 3x3 inverse of (S + eps*I), S row-major 9 floats (exactly symmetric
// by construction: S = 0.1*L*L^T + 0.1*I). Matches reference adjugate/det.
__device__ __forceinline__ void inv3_sym(const float* __restrict__ S,
                                         float& i00, float& i01, float& i02,
                                         float& i11, float& i12, float& i22) {
    float a00 = S[0] + EPSV, a01 = S[1], a02 = S[2];
    float a11 = S[4] + EPSV, a12 = S[5];
    float a22 = S[8] + EPSV;
    float c00 = a11 * a22 - a12 * a12;
    float c01 = a02 * a12 - a01 * a22;
    float c02 = a01 * a12 - a02 * a11;
    float c11 = a00 * a22 - a02 * a02;
    float c12 = a01 * a02 - a00 * a12;
    float c22 = a00 * a11 - a01 * a01;
    float det = a00 * c00 + a01 * c01 + a02 * c02;
    float r = 1.0f / det;
    i00 = c00 * r; i01 = c01 * r; i02 = c02 * r;
    i11 = c11 * r; i12 = c12 * r; i22 = c22 * r;
}

// Prep: invert all child (B*N) and parent (B*K) covariances into packed ws
// layout. Also reduces mask sum into acc[2].
//   cA[idx] = (mu0, mu1, mu2, i00)   cB[idx] = (i01, i02, i11, i12)   cC[idx] = i22
__global__ __launch_bounds__(BLOCK) void prep_kernel(
        const float* __restrict__ mu_c, const float* __restrict__ Sg_c,
        const float* __restrict__ mu_p, const float* __restrict__ Sg_p,
        const float* __restrict__ mask, float* __restrict__ acc,
        float4* __restrict__ cA, float4* __restrict__ cB, float* __restrict__ cC,
        float4* __restrict__ pA, float4* __restrict__ pB, float* __restrict__ pC) {
    int idx = blockIdx.x * BLOCK + threadIdx.x;
    float mval = 0.0f;
    if (idx < BB * NN) {
        float i00, i01, i02, i11, i12, i22;
        inv3_sym(Sg_c + (size_t)idx * 9, i00, i01, i02, i11, i12, i22);
        const float* mu = mu_c + (size_t)idx * 3;
        cA[idx] = make_float4(mu[0], mu[1], mu[2], i00);
        cB[idx] = make_float4(i01, i02, i11, i12);
        cC[idx] = i22;
        mval = mask[idx];
    } else if (idx < BB * NN + BB * KK) {
        int p = idx - BB * NN;
        float i00, i01, i02, i11, i12, i22;
        inv3_sym(Sg_p + (size_t)p * 9, i00, i01, i02, i11, i12, i22);
        const float* mu = mu_p + (size_t)p * 3;
        pA[p] = make_float4(mu[0], mu[1], mu[2], i00);
        pB[p] = make_float4(i01, i02, i11, i12);
        pC[p] = i22;
    }
    // wave-64 reduce of mask values, one atomic per wave
    #pragma unroll
    for (int off = 32; off > 0; off >>= 1) mval += __shfl_down(mval, off);
    if ((threadIdx.x & 63) == 0) atomicAdd(acc + 2, mval);
}

// Main: block covers ROWS consecutive rows (same batch since N%ROWS==0).
// Parent table for the batch staged in LDS (18 KB). Each thread handles 2 rows
// per parent fetch (parent LDS traffic halved). Accumulates
//   sp = sum maha_p * A * mask,  sc = sum maha_c * A * mask.
__global__ __launch_bounds__(BLOCK) void main_kernel(
        const float* __restrict__ A,
        const float4* __restrict__ cA, const float4* __restrict__ cB,
        const float* __restrict__ cC, const float* __restrict__ mask,
        const float4* __restrict__ pA, const float4* __restrict__ pB,
        const float* __restrict__ pC, float* __restrict__ acc) {
    __shared__ float4 sP0[KK];   // mu0,mu1,mu2,i00
    __shared__ float4 sP1[KK];   // i01,i02,i11,i12
    __shared__ float  sP2[KK];   // i22
    __shared__ float  red[8];

    const int tid = threadIdx.x;
    const int rowStart = blockIdx.x * ROWS;       // global row index b*N+n
    const int b = rowStart / NN;

    // Stage parent table for batch b (coalesced b128 loads/stores).
    #pragma unroll
    for (int k = tid; k < KK; k += BLOCK) {
        sP0[k] = pA[b * KK + k];
        sP1[k] = pB[b * KK + k];
        sP2[k] = pC[b * KK + k];
    }
    __syncthreads();

    float sp = 0.0f, sc = 0.0f;

    for (int rg = 0; rg < ROWS; rg += 2) {
        const int r0 = rowStart + rg;
        const int r1 = r0 + 1;
        // wave-uniform indices -> scalar loads
        const float4 c0A = cA[r0], c0B = cB[r0];
        const float  c0C = cC[r0], m0 = mask[r0];
        const float4 c1A = cA[r1], c1B = cB[r1];
        const float  c1C = cC[r1], m1 = mask[r1];
        const float* __restrict__ A0 = A + (size_t)r0 * KK;
        const float* __restrict__ A1 = A + (size_t)r1 * KK;

        #pragma unroll
        for (int ko = 0; ko < KK; ko += BLOCK) {
            const int k = ko + tid;
            const float4 p0 = sP0[k];
            const float4 p1 = sP1[k];
            const float  p2 = sP2[k];
            const float a0 = A0[k] * m0;
            const float a1 = A1[k] * m1;
            // row 0
            {
                float d0 = c0A.x - p0.x, d1 = c0A.y - p0.y, d2 = c0A.z - p0.z;
                float e00 = d0 * d0, e11 = d1 * d1, e22 = d2 * d2;
                float e01 = d0 * d1, e02 = d0 * d2, e12 = d1 * d2;
                float qp = p0.w * e00 + p1.z * e11 + p2 * e22
                         + 2.0f * (p1.x * e01 + p1.y * e02 + p1.w * e12);
                float qc = c0A.w * e00 + c0B.z * e11 + c0C * e22
                         + 2.0f * (c0B.x * e01 + c0B.y * e02 + c0B.w * e12);
                sp += qp * a0;
                sc += qc * a0;
            }
            // row 1
            {
                float d0 = c1A.x - p0.x, d1 = c1A.y - p0.y, d2 = c1A.z - p0.z;
                float e00 = d0 * d0, e11 = d1 * d1, e22 = d2 * d2;
                float e01 = d0 * d1, e02 = d0 * d2, e12 = d1 * d2;
                float qp = p0.w * e00 + p1.z * e11 + p2 * e22
                         + 2.0f * (p1.x * e01 + p1.y * e02 + p1.w * e12);
                float qc = c1A.w * e00 + c1B.z * e11 + c1C * e22
                         + 2.0f * (c1B.x * e01 + c1B.y * e02 + c1B.w * e12);
                sp += qp * a1;
                sc += qc * a1;
            }
        }
    }

    // block reduction: wave-64 shuffle, then cross-wave via LDS
    #pragma unroll
    for (int off = 32; off > 0; off >>= 1) {
        sp += __shfl_down(sp, off);
        sc += __shfl_down(sc, off);
    }
    const int wave = tid >> 6;
    if ((tid & 63) == 0) { red[wave * 2] = sp; red[wave * 2 + 1] = sc; }
    __syncthreads();
    if (tid == 0) {
        float tp = red[0] + red[2] + red[4] + red[6];
        float tc = red[1] + red[3] + red[5] + red[7];
        atomicAdd(acc + 0, tp);
        atomicAdd(acc + 1, tc);
    }
}

__global__ void finalize_kernel(const float* __restrict__ acc,
                                float* __restrict__ out) {
    if (threadIdx.x == 0) {
        float denom = fmaxf(acc[2], 1.0f);
        float tp = acc[0], tc = acc[1];
        out[0] = (W_P * tp + W_C * tc) / denom;
        out[1] = tp / denom;
        out[2] = tc / denom;
    }
}

extern "C" void kernel_launch(void* const* d_in, const int* in_sizes, int n_in,
                              void* d_out, int out_size, void* d_ws, size_t ws_size,
                              hipStream_t stream) {
    const float* mu_c = (const float*)d_in[0];
    const float* Sg_c = (const float*)d_in[1];
    const float* mu_p = (const float*)d_in[2];
    const float* Sg_p = (const float*)d_in[3];
    const float* A    = (const float*)d_in[4];
    const float* mask = (const float*)d_in[5];
    float* out = (float*)d_out;

    // ws layout (hipMalloc'd base -> 16B aligned throughout):
    //   acc[4] | cA float4[B*N] | cB float4[B*N] | cC float[B*N]
    //          | pA float4[B*K] | pB float4[B*K] | pC float[B*K]
    char* ws = (char*)d_ws;
    float*  acc = (float*)ws;
    float4* cA  = (float4*)(ws + 16);
    float4* cB  = cA + BB * NN;
    float*  cC  = (float*)(cB + BB * NN);
    float4* pA  = (float4*)(cC + BB * NN);   // offset 589840, 16B-aligned
    float4* pB  = pA + BB * KK;
    float*  pC  = (float*)(pB + BB * KK);

    hipMemsetAsync(acc, 0, 16, stream);

    int prep_items = BB * NN + BB * KK;
    prep_kernel<<<(prep_items + BLOCK - 1) / BLOCK, BLOCK, 0, stream>>>(
        mu_c, Sg_c, mu_p, Sg_p, mask, acc, cA, cB, cC, pA, pB, pC);

    main_kernel<<<(BB * NN) / ROWS, BLOCK, 0, stream>>>(
        A, cA, cB, cC, mask, pA, pB, pC, acc);

    finalize_kernel<<<1, 64, 0, stream>>>(acc, out);
}

// Round 2
// 96.130 us; speedup vs baseline: 1.2578x; 1.2578x over previous
//
#include <hip/hip_runtime.h>

// Problem constants (fixed by setup_inputs): B=4, N=4096, K=512.
#define BB 4
#define NN 4096
#define KK 512
#define BLOCK 256
#define ROWS 16                      // rows per block -> (BB*NN)/ROWS = 1024 blocks
#define GRID ((BB * NN) / ROWS)      // 1024

static constexpr float W_P  = 1.0f;
static constexpr float W_C  = 1.0f;
static constexpr float EPSV = 1e-6f;

// Symmetric 3x3 inverse of (S + eps*I), S row-major 9 floats (S is exactly
// symmetric by construction: 0.1*L*L^T + 0.1*I). Matches reference adjugate/det.
__device__ __forceinline__ void inv3_sym(const float* __restrict__ S,
                                         float& i00, float& i01, float& i02,
                                         float& i11, float& i12, float& i22) {
    float a00 = S[0] + EPSV, a01 = S[1], a02 = S[2];
    float a11 = S[4] + EPSV, a12 = S[5];
    float a22 = S[8] + EPSV;
    float c00 = a11 * a22 - a12 * a12;
    float c01 = a02 * a12 - a01 * a22;
    float c02 = a01 * a12 - a02 * a11;
    float c11 = a00 * a22 - a02 * a02;
    float c12 = a01 * a02 - a00 * a12;
    float c22 = a00 * a11 - a01 * a01;
    float det = a00 * c00 + a01 * c01 + a02 * c02;
    float r = 1.0f / det;
    i00 = c00 * r; i01 = c01 * r; i02 = c02 * r;
    i11 = c11 * r; i12 = c12 * r; i22 = c22 * r;
}

// Fused kernel: per block, compute the batch's 512 parent inverses into LDS
// (cheap: ~25 KB of L2-resident reads, ~70 VALU ops/thread) and the block's 16
// child inverses into LDS, then stream A once. Off-diagonal inverse entries are
// pre-doubled at staging (2*x is exact in fp32) to save a multiply per element.
// Each thread handles 2 rows per parent-LDS fetch. Partials (no atomics, no
// init needed) go to part[] : [0..GRID) = sum maha_p*A*mask, [GRID..2G) =
// sum maha_c*A*mask, [2G..3G) = block mask sum.
__global__ __launch_bounds__(BLOCK) void main_kernel(
        const float* __restrict__ mu_c, const float* __restrict__ Sg_c,
        const float* __restrict__ mu_p, const float* __restrict__ Sg_p,
        const float* __restrict__ A,    const float* __restrict__ mask,
        float* __restrict__ part) {
    __shared__ float4 sP0[KK];     // mu0, mu1, mu2, i00
    __shared__ float4 sP1[KK];     // 2*i01, 2*i02, i11, 2*i12
    __shared__ float  sP2[KK];     // i22
    __shared__ float4 sC0[ROWS];
    __shared__ float4 sC1[ROWS];
    __shared__ float  sC2[ROWS];
    __shared__ float  sM[ROWS];
    __shared__ float  red[8];

    const int tid = threadIdx.x;
    const int rowStart = blockIdx.x * ROWS;   // global row index b*N+n
    const int b = rowStart / NN;

    // Parent staging + inversion (512 parents / 256 threads = 2 each).
    for (int k = tid; k < KK; k += BLOCK) {
        const int gp = b * KK + k;
        float i00, i01, i02, i11, i12, i22;
        inv3_sym(Sg_p + (size_t)gp * 9, i00, i01, i02, i11, i12, i22);
        const float* mu = mu_p + (size_t)gp * 3;
        sP0[k] = make_float4(mu[0], mu[1], mu[2], i00);
        sP1[k] = make_float4(2.0f * i01, 2.0f * i02, i11, 2.0f * i12);
        sP2[k] = i22;
    }
    // Child staging + inversion (first 16 threads).
    if (tid < ROWS) {
        const int r = rowStart + tid;
        float i00, i01, i02, i11, i12, i22;
        inv3_sym(Sg_c + (size_t)r * 9, i00, i01, i02, i11, i12, i22);
        const float* mu = mu_c + (size_t)r * 3;
        sC0[tid] = make_float4(mu[0], mu[1], mu[2], i00);
        sC1[tid] = make_float4(2.0f * i01, 2.0f * i02, i11, 2.0f * i12);
        sC2[tid] = i22;
        sM[tid] = mask[r];
    }
    __syncthreads();

    float sp = 0.0f, sc = 0.0f;

    for (int rg = 0; rg < ROWS; rg += 2) {
        // wave-uniform LDS reads -> broadcast, no conflicts
        const float4 c0A = sC0[rg],     c0B = sC1[rg];
        const float  c0C = sC2[rg],     m0  = sM[rg];
        const float4 c1A = sC0[rg + 1], c1B = sC1[rg + 1];
        const float  c1C = sC2[rg + 1], m1  = sM[rg + 1];
        const float* __restrict__ A0 = A + (size_t)(rowStart + rg) * KK;
        const float* __restrict__ A1 = A0 + KK;

        #pragma unroll
        for (int ko = 0; ko < KK; ko += BLOCK) {
            const int k = ko + tid;
            const float4 p0 = sP0[k];
            const float4 p1 = sP1[k];
            const float  p2 = sP2[k];
            const float a0 = A0[k] * m0;
            const float a1 = A1[k] * m1;
            {   // row 0
                float d0 = c0A.x - p0.x, d1 = c0A.y - p0.y, d2 = c0A.z - p0.z;
                float e00 = d0 * d0, e11 = d1 * d1, e22 = d2 * d2;
                float e01 = d0 * d1, e02 = d0 * d2, e12 = d1 * d2;
                float qp = p0.w * e00 + p1.z * e11 + p2 * e22
                         + p1.x * e01 + p1.y * e02 + p1.w * e12;
                float qc = c0A.w * e00 + c0B.z * e11 + c0C * e22
                         + c0B.x * e01 + c0B.y * e02 + c0B.w * e12;
                sp += qp * a0;
                sc += qc * a0;
            }
            {   // row 1
                float d0 = c1A.x - p0.x, d1 = c1A.y - p0.y, d2 = c1A.z - p0.z;
                float e00 = d0 * d0, e11 = d1 * d1, e22 = d2 * d2;
                float e01 = d0 * d1, e02 = d0 * d2, e12 = d1 * d2;
                float qp = p0.w * e00 + p1.z * e11 + p2 * e22
                         + p1.x * e01 + p1.y * e02 + p1.w * e12;
                float qc = c1A.w * e00 + c1B.z * e11 + c1C * e22
                         + c1B.x * e01 + c1B.y * e02 + c1B.w * e12;
                sp += qp * a1;
                sc += qc * a1;
            }
        }
    }

    // Block reduction: wave-64 shuffle, then cross-wave via LDS.
    #pragma unroll
    for (int off = 32; off > 0; off >>= 1) {
        sp += __shfl_down(sp, off);
        sc += __shfl_down(sc, off);
    }
    const int wave = tid >> 6;
    if ((tid & 63) == 0) { red[wave * 2] = sp; red[wave * 2 + 1] = sc; }
    __syncthreads();
    if (tid == 0) {
        part[blockIdx.x]            = red[0] + red[2] + red[4] + red[6];
        part[GRID + blockIdx.x]     = red[1] + red[3] + red[5] + red[7];
        float msum = 0.0f;
        #pragma unroll
        for (int i = 0; i < ROWS; ++i) msum += sM[i];
        part[2 * GRID + blockIdx.x] = msum;
    }
}

// Reduce the 3*GRID partials and write the 3 outputs.
__global__ __launch_bounds__(256) void finalize_kernel(
        const float* __restrict__ part, float* __restrict__ out) {
    __shared__ float red[12];
    const int tid = threadIdx.x;
    float tp = 0.0f, tc = 0.0f, tm = 0.0f;
    for (int i = tid; i < GRID; i += 256) {
        tp += part[i];
        tc += part[GRID + i];
        tm += part[2 * GRID + i];
    }
    #pragma unroll
    for (int off = 32; off > 0; off >>= 1) {
        tp += __shfl_down(tp, off);
        tc += __shfl_down(tc, off);
        tm += __shfl_down(tm, off);
    }
    const int wave = tid >> 6;
    if ((tid & 63) == 0) {
        red[wave * 3] = tp; red[wave * 3 + 1] = tc; red[wave * 3 + 2] = tm;
    }
    __syncthreads();
    if (tid == 0) {
        float sp = red[0] + red[3] + red[6] + red[9];
        float sc = red[1] + red[4] + red[7] + red[10];
        float sm = red[2] + red[5] + red[8] + red[11];
        float denom = fmaxf(sm, 1.0f);
        out[0] = (W_P * sp + W_C * sc) / denom;
        out[1] = sp / denom;
        out[2] = sc / denom;
    }
}

extern "C" void kernel_launch(void* const* d_in, const int* in_sizes, int n_in,
                              void* d_out, int out_size, void* d_ws, size_t ws_size,
                              hipStream_t stream) {
    const float* mu_c = (const float*)d_in[0];
    const float* Sg_c = (const float*)d_in[1];
    const float* mu_p = (const float*)d_in[2];
    const float* Sg_p = (const float*)d_in[3];
    const float* A    = (const float*)d_in[4];
    const float* mask = (const float*)d_in[5];
    float* out  = (float*)d_out;
    float* part = (float*)d_ws;   // 3*GRID floats, all written by main_kernel

    main_kernel<<<GRID, BLOCK, 0, stream>>>(mu_c, Sg_c, mu_p, Sg_p, A, mask, part);
    finalize_kernel<<<1, 256, 0, stream>>>(part, out);
}